// Round 1
// baseline (31.784 us; speedup 1.0000x reference)
//
#include <hip/hip_runtime.h>
#include <hip/hip_bf16.h>

#define NFIELDS 32
#define DDIM 64
#define NPAIR 496   // 32*31/2

typedef __attribute__((ext_vector_type(8))) __bf16 bf16x8;
typedef __attribute__((ext_vector_type(4))) float f32x4;

__device__ __forceinline__ int pair_idx(int i, int j) {
    // number of pairs before row i = 31*i - i*(i-1)/2 ; then offset (j-i-1)
    return i * 31 - (i * (i - 1)) / 2 + (j - i - 1);
}

__global__ __launch_bounds__(256) void inner_product_kernel(
        const float* __restrict__ x, float* __restrict__ out, int nbatch) {
    const int gtid = blockIdx.x * blockDim.x + threadIdx.x;
    const int wave = gtid >> 6;        // one wave per batch element
    const int lane = threadIdx.x & 63;
    if (wave >= nbatch) return;

    const float* xb = x + (size_t)wave * (NFIELDS * DDIM);
    const int r = lane & 15;   // row within 16-row tile
    const int g = lane >> 4;   // k-group 0..3 (8 consecutive k each)

    // F[rt][kt]: fragment of X rows [rt*16, rt*16+16), k in [kt*32, kt*32+32).
    // For Gram (C = X * X^T) this same data serves as BOTH the A-fragment
    // (rows) and the B-fragment (cols of X^T) — layouts coincide lane-for-lane.
    bf16x8 F[2][2];
#pragma unroll
    for (int rt = 0; rt < 2; ++rt) {
        const float* rowp = xb + (rt * 16 + r) * DDIM + g * 8;
#pragma unroll
        for (int kt = 0; kt < 2; ++kt) {
            const float4* p = reinterpret_cast<const float4*>(rowp + kt * 32);
            float4 a = p[0];   // 32B contiguous per lane, fully coalesced
            float4 c = p[1];
            bf16x8 f;
            f[0] = (__bf16)a.x; f[1] = (__bf16)a.y; f[2] = (__bf16)a.z; f[3] = (__bf16)a.w;
            f[4] = (__bf16)c.x; f[5] = (__bf16)c.y; f[6] = (__bf16)c.z; f[7] = (__bf16)c.w;
            F[rt][kt] = f;
        }
    }

    f32x4 acc00 = {0.f, 0.f, 0.f, 0.f};
    f32x4 acc01 = {0.f, 0.f, 0.f, 0.f};
    f32x4 acc11 = {0.f, 0.f, 0.f, 0.f};
    // tile (rt,ct): C[i][j] = sum_k X[rt*16+i][k] * X[ct*16+j][k]
    acc00 = __builtin_amdgcn_mfma_f32_16x16x32_bf16(F[0][0], F[0][0], acc00, 0, 0, 0);
    acc00 = __builtin_amdgcn_mfma_f32_16x16x32_bf16(F[0][1], F[0][1], acc00, 0, 0, 0);
    acc01 = __builtin_amdgcn_mfma_f32_16x16x32_bf16(F[0][0], F[1][0], acc01, 0, 0, 0);
    acc01 = __builtin_amdgcn_mfma_f32_16x16x32_bf16(F[0][1], F[1][1], acc01, 0, 0, 0);
    acc11 = __builtin_amdgcn_mfma_f32_16x16x32_bf16(F[1][0], F[1][0], acc11, 0, 0, 0);
    acc11 = __builtin_amdgcn_mfma_f32_16x16x32_bf16(F[1][1], F[1][1], acc11, 0, 0, 0);

    // C/D layout (m89-verified): col = lane&15, row = (lane>>4)*4 + reg
    float* ob = out + (size_t)wave * NPAIR;
    const int col = lane & 15;
    const int rowb = (lane >> 4) * 4;
#pragma unroll
    for (int v = 0; v < 4; ++v) {       // tile (0,0): i,j in [0,16)
        int i = rowb + v, j = col;
        if (j > i) ob[pair_idx(i, j)] = acc00[v];
    }
#pragma unroll
    for (int v = 0; v < 4; ++v) {       // tile (0,1): i in [0,16), j in [16,32) — all valid
        int i = rowb + v, j = 16 + col;
        ob[pair_idx(i, j)] = acc01[v];
    }
#pragma unroll
    for (int v = 0; v < 4; ++v) {       // tile (1,1): i,j in [16,32)
        int i = 16 + rowb + v, j = 16 + col;
        if (j > i) ob[pair_idx(i, j)] = acc11[v];
    }
}

extern "C" void kernel_launch(void* const* d_in, const int* in_sizes, int n_in,
                              void* d_out, int out_size, void* d_ws, size_t ws_size,
                              hipStream_t stream) {
    const float* x = (const float*)d_in[0];
    float* out = (float*)d_out;
    const int nbatch = in_sizes[0] / (NFIELDS * DDIM);   // 16384
    const int waves_per_block = 4;                       // 256 threads
    const int nblocks = (nbatch + waves_per_block - 1) / waves_per_block;
    inner_product_kernel<<<nblocks, 256, 0, stream>>>(x, out, nbatch);
}